// Round 2
// baseline (419.432 us; speedup 1.0000x reference)
//
#include <hip/hip_runtime.h>
#include <hip/hip_bf16.h>

#define BB 8
#define NN 2048
#define MM 2048
#define DD 512

typedef __attribute__((ext_vector_type(8))) short bf16x8;
typedef __attribute__((ext_vector_type(4))) float f32x4;
typedef __attribute__((ext_vector_type(8))) unsigned short u16x8;

__device__ __forceinline__ unsigned short f2bf(float x){
  unsigned int u = __float_as_uint(x);
  u += 0x7fffu + ((u>>16)&1u);   // round-to-nearest-even
  return (unsigned short)(u>>16);
}
__device__ __forceinline__ float bf2f(unsigned short h){
  return __uint_as_float(((unsigned int)h)<<16);
}
__device__ __forceinline__ f32x4 mfma16(bf16x8 a, bf16x8 b, f32x4 c){
  return __builtin_amdgcn_mfma_f32_16x16x32_bf16(a, b, c, 0, 0, 0);
}

// ---------------------------------------------------------------------------
// split2: f32 -> hi/lo bf16 (lo==nullptr -> hi only), float4-vectorized
// ---------------------------------------------------------------------------
__global__ __launch_bounds__(256) void split2_kernel(const float* __restrict__ in,
    unsigned short* __restrict__ hi, unsigned short* __restrict__ lo, int n4){
  int i = blockIdx.x*256 + threadIdx.x;
  const int stride = gridDim.x*256;
  for (; i < n4; i += stride){
    float4 v = ((const float4*)in)[i];
    ushort4 h; h.x=f2bf(v.x); h.y=f2bf(v.y); h.z=f2bf(v.z); h.w=f2bf(v.w);
    ((ushort4*)hi)[i] = h;
    if (lo){
      ushort4 l;
      l.x=f2bf(v.x-bf2f(h.x)); l.y=f2bf(v.y-bf2f(h.y));
      l.z=f2bf(v.z-bf2f(h.z)); l.w=f2bf(v.w-bf2f(h.w));
      ((ushort4*)lo)[i] = l;
    }
  }
}

// ---------------------------------------------------------------------------
// K0: At[j][i] = sum_e Wq[e][i] * Wk[e][j], written split hi/lo bf16
// ---------------------------------------------------------------------------
__global__ __launch_bounds__(256) void at_kernel(const float* __restrict__ Wq,
                                                 const float* __restrict__ Wk,
                                                 unsigned short* __restrict__ atHi,
                                                 unsigned short* __restrict__ atLo){
  const int i0 = blockIdx.x * 32, j0 = blockIdx.y * 32;
  __shared__ float q_s[32][33];
  __shared__ float k_s[32][33];
  const int t = threadIdx.x;
  const int tx = t & 15, ty = t >> 4;
  float acc[2][2] = {{0.f,0.f},{0.f,0.f}};
  for (int e0 = 0; e0 < DD; e0 += 32){
    __syncthreads();
#pragma unroll
    for (int p = 0; p < 4; ++p){
      int idx = t + 256*p;
      int e = idx >> 5, c = idx & 31;
      q_s[e][c] = Wq[(size_t)(e0+e)*DD + i0 + c];
      k_s[e][c] = Wk[(size_t)(e0+e)*DD + j0 + c];
    }
    __syncthreads();
#pragma unroll 8
    for (int e = 0; e < 32; ++e){
      float q0 = q_s[e][2*tx], q1 = q_s[e][2*tx+1];
      float k0 = k_s[e][2*ty], k1 = k_s[e][2*ty+1];
      acc[0][0] += k0*q0; acc[0][1] += k0*q1;
      acc[1][0] += k1*q0; acc[1][1] += k1*q1;
    }
  }
#pragma unroll
  for (int a = 0; a < 2; ++a)
#pragma unroll
    for (int b = 0; b < 2; ++b){
      float v = acc[a][b];
      size_t idx = (size_t)(j0 + 2*ty + a)*DD + i0 + 2*tx + b;
      unsigned short h = f2bf(v);
      atHi[idx] = h;
      atLo[idx] = f2bf(v - bf2f(h));
    }
}

// c2[d] = sum_e bq[e] * Wk[e][d]
__global__ __launch_bounds__(256) void c2_kernel(const float* __restrict__ bq,
                                                 const float* __restrict__ Wk,
                                                 float* __restrict__ c2){
  int d = blockIdx.x * 256 + threadIdx.x;
  float a = 0.f;
  for (int e = 0; e < DD; ++e) a += bq[e] * Wk[(size_t)e*DD + d];
  c2[d] = a;
}

// s[b*M+m] = dot(camera[b,m,:], c2)
__global__ __launch_bounds__(64) void s_kernel(const float* __restrict__ cam,
                                               const float* __restrict__ c2,
                                               float* __restrict__ svec){
  size_t row = blockIdx.x;
  const float* y = cam + row * DD;
  int l = threadIdx.x;
  float a = 0.f;
#pragma unroll
  for (int i = 0; i < 8; ++i) a += y[l + 64*i] * c2[l + 64*i];
  for (int o = 32; o; o >>= 1) a += __shfl_xor(a, o);
  if (l == 0) svec[row] = a;
}

// ---------------------------------------------------------------------------
// x3-precision GEMM, BT form: O[row,col] = sum_k A[row,k]*B[col,k]
// A = Ahi+Alo, B = Bhi+Blo (bf16 splits), acc = hh + hl + lh.
// Block 128(M) x 256(N), 4 waves, wave tile 128x64 (8x4 fragments 16x16x32).
// MODE 2: f32 out = conf[row]*(acc + svec[col]).  MODE 4: hi/lo bf16 out.
// ---------------------------------------------------------------------------
template<int MODE>
__global__ __launch_bounds__(256, 2) void gemm_x3(
    const unsigned short* __restrict__ Ahg, const unsigned short* __restrict__ Alg,
    long sA, int lda,
    const unsigned short* __restrict__ Bhg, const unsigned short* __restrict__ Blg,
    long sB, int ldb,
    void* __restrict__ O1, void* __restrict__ O2, long sO, int ldo, int K,
    const float* __restrict__ conf, const float* __restrict__ svec)
{
  __shared__ __attribute__((aligned(16))) unsigned short Ah[128][40];
  __shared__ __attribute__((aligned(16))) unsigned short Al[128][40];
  __shared__ __attribute__((aligned(16))) unsigned short Bh[256][40];
  __shared__ __attribute__((aligned(16))) unsigned short Bl[256][40];

  const int t = threadIdx.x;
  const int bn = blockIdx.x, bm = blockIdx.y, bz = blockIdx.z;
  const int lane = t & 63, w = t >> 6;
  const int lr = lane & 15, lk = (lane >> 4) << 3;

  f32x4 acc[8][4];
#pragma unroll
  for (int m = 0; m < 8; ++m)
#pragma unroll
    for (int n = 0; n < 4; ++n){ f32x4 z = {0.f,0.f,0.f,0.f}; acc[m][n] = z; }

  const unsigned short* Ahp = Ahg + (size_t)bz*(size_t)sA + ((size_t)bm*128)*(size_t)lda;
  const unsigned short* Alp = Alg + (size_t)bz*(size_t)sA + ((size_t)bm*128)*(size_t)lda;
  const unsigned short* Bhp = Bhg + (size_t)bz*(size_t)sB + ((size_t)bn*256)*(size_t)ldb;
  const unsigned short* Blp = Blg + (size_t)bz*(size_t)sB + ((size_t)bn*256)*(size_t)ldb;

  const int sr = t >> 2;          // 0..63
  const int sc = (t & 3) * 8;     // 0,8,16,24

  for (int k0 = 0; k0 < K; k0 += 32){
    __syncthreads();
#pragma unroll
    for (int p = 0; p < 2; ++p){
      int r = sr + 64*p;
      *(u16x8*)&Ah[r][sc] = *(const u16x8*)(Ahp + (size_t)r*lda + k0 + sc);
      *(u16x8*)&Al[r][sc] = *(const u16x8*)(Alp + (size_t)r*lda + k0 + sc);
    }
#pragma unroll
    for (int p = 0; p < 4; ++p){
      int r = sr + 64*p;
      *(u16x8*)&Bh[r][sc] = *(const u16x8*)(Bhp + (size_t)r*ldb + k0 + sc);
      *(u16x8*)&Bl[r][sc] = *(const u16x8*)(Blp + (size_t)r*ldb + k0 + sc);
    }
    __syncthreads();

    bf16x8 bhf[4], blf[4];
#pragma unroll
    for (int n = 0; n < 4; ++n){
      bhf[n] = *(const bf16x8*)&Bh[w*64 + n*16 + lr][lk];
      blf[n] = *(const bf16x8*)&Bl[w*64 + n*16 + lr][lk];
    }
#pragma unroll
    for (int m = 0; m < 8; ++m){
      bf16x8 ahf = *(const bf16x8*)&Ah[m*16 + lr][lk];
      bf16x8 alf = *(const bf16x8*)&Al[m*16 + lr][lk];
#pragma unroll
      for (int n = 0; n < 4; ++n){
        acc[m][n] = mfma16(ahf, bhf[n], acc[m][n]);
        acc[m][n] = mfma16(ahf, blf[n], acc[m][n]);
        acc[m][n] = mfma16(alf, bhf[n], acc[m][n]);
      }
    }
  }

  const int ocol0 = bn*256 + w*64;
  const int orow0 = bm*128;
#pragma unroll
  for (int m = 0; m < 8; ++m){
#pragma unroll
    for (int n = 0; n < 4; ++n){
      int col  = ocol0 + n*16 + lr;
      int row0 = orow0 + m*16 + ((lane >> 4) << 2);
#pragma unroll
      for (int r = 0; r < 4; ++r){
        int row = row0 + r;
        float v = acc[m][n][r];
        if constexpr (MODE == 2){
          ((float*)O1)[(size_t)bz*(size_t)sO + (size_t)row*ldo + col]
              = conf[bz*NN + row] * (v + svec[bz*MM + col]);
        } else { // MODE 4: hi/lo bf16
          unsigned short h = f2bf(v);
          unsigned short l = f2bf(v - bf2f(h));
          ((unsigned short*)O1)[(size_t)bz*(size_t)sO + (size_t)row*ldo + col] = h;
          ((unsigned short*)O2)[(size_t)bz*(size_t)sO + (size_t)row*ldo + col] = l;
        }
      }
    }
  }
}

// ---------------------------------------------------------------------------
// Plain bf16 GEMM, BT form.  Block 128x128, 4 waves 2x2, wave 64x64 (4x4 frags).
// MODE 0: f32 out.  MODE 1: bf16 out + bias[row].
// ---------------------------------------------------------------------------
template<int MODE>
__global__ __launch_bounds__(256) void gemm_bf(
    const unsigned short* __restrict__ Ag, long sA, int lda,
    const unsigned short* __restrict__ Bg, long sB, int ldb,
    void* __restrict__ O1, long sO, int ldo, int K,
    const float* __restrict__ bias)
{
  __shared__ __attribute__((aligned(16))) unsigned short Ah[128][40];
  __shared__ __attribute__((aligned(16))) unsigned short Bh[128][40];

  const int t = threadIdx.x;
  const int bn = blockIdx.x, bm = blockIdx.y, bz = blockIdx.z;
  const int lane = t & 63, w = t >> 6;
  const int wrow = w >> 1, wcol = w & 1;
  const int lr = lane & 15, lk = (lane >> 4) << 3;

  f32x4 acc[4][4];
#pragma unroll
  for (int m = 0; m < 4; ++m)
#pragma unroll
    for (int n = 0; n < 4; ++n){ f32x4 z = {0.f,0.f,0.f,0.f}; acc[m][n] = z; }

  const unsigned short* Ap = Ag + (size_t)bz*(size_t)sA + ((size_t)bm*128)*(size_t)lda;
  const unsigned short* Bp = Bg + (size_t)bz*(size_t)sB + ((size_t)bn*128)*(size_t)ldb;

  const int sr = t >> 2;          // 0..63
  const int sc = (t & 3) * 8;

  for (int k0 = 0; k0 < K; k0 += 32){
    __syncthreads();
#pragma unroll
    for (int p = 0; p < 2; ++p){
      int r = sr + 64*p;
      *(u16x8*)&Ah[r][sc] = *(const u16x8*)(Ap + (size_t)r*lda + k0 + sc);
      *(u16x8*)&Bh[r][sc] = *(const u16x8*)(Bp + (size_t)r*ldb + k0 + sc);
    }
    __syncthreads();

    bf16x8 af[4], bf[4];
#pragma unroll
    for (int m = 0; m < 4; ++m) af[m] = *(const bf16x8*)&Ah[wrow*64 + m*16 + lr][lk];
#pragma unroll
    for (int n = 0; n < 4; ++n) bf[n] = *(const bf16x8*)&Bh[wcol*64 + n*16 + lr][lk];
#pragma unroll
    for (int m = 0; m < 4; ++m)
#pragma unroll
      for (int n = 0; n < 4; ++n)
        acc[m][n] = mfma16(af[m], bf[n], acc[m][n]);
  }

  const int orow = bm*128 + wrow*64;
  const int ocol = bn*128 + wcol*64;
#pragma unroll
  for (int m = 0; m < 4; ++m){
#pragma unroll
    for (int n = 0; n < 4; ++n){
      int col  = ocol + n*16 + lr;
      int row0 = orow + m*16 + ((lane >> 4) << 2);
#pragma unroll
      for (int r = 0; r < 4; ++r){
        int row = row0 + r;
        float v = acc[m][n][r];
        if constexpr (MODE == 1){
          ((unsigned short*)O1)[(size_t)bz*(size_t)sO + (size_t)row*ldo + col] = f2bf(v + bias[row]);
        } else {
          ((float*)O1)[(size_t)bz*(size_t)sO + (size_t)row*ldo + col] = v;
        }
      }
    }
  }
}

// ---------------------------------------------------------------------------
// Row softmax over M=2048, f32 in, bf16 out in-place (row's first 4KB)
// ---------------------------------------------------------------------------
__global__ __launch_bounds__(256) void softmax_kernel(float* __restrict__ scores){
  const size_t row = blockIdx.x;
  float* src = scores + row * MM;
  unsigned short* dst = (unsigned short*)scores + row * (size_t)(2*MM);
  const int t = threadIdx.x;

  float4 v0 = ((const float4*)src)[t];
  float4 v1 = ((const float4*)src)[t + 256];

  float mx = fmaxf(fmaxf(fmaxf(v0.x,v0.y), fmaxf(v0.z,v0.w)),
                   fmaxf(fmaxf(v1.x,v1.y), fmaxf(v1.z,v1.w)));
  for (int o = 32; o; o >>= 1) mx = fmaxf(mx, __shfl_xor(mx, o));
  __shared__ float red[4];
  if ((t & 63) == 0) red[t >> 6] = mx;
  __syncthreads();
  mx = fmaxf(fmaxf(red[0], red[1]), fmaxf(red[2], red[3]));

  float e0x = __expf(v0.x - mx), e0y = __expf(v0.y - mx);
  float e0z = __expf(v0.z - mx), e0w = __expf(v0.w - mx);
  float e1x = __expf(v1.x - mx), e1y = __expf(v1.y - mx);
  float e1z = __expf(v1.z - mx), e1w = __expf(v1.w - mx);
  float s = e0x+e0y+e0z+e0w+e1x+e1y+e1z+e1w;
  for (int o = 32; o; o >>= 1) s += __shfl_xor(s, o);
  __syncthreads();
  if ((t & 63) == 0) red[t >> 6] = s;
  __syncthreads();
  float inv = 1.f / (red[0] + red[1] + red[2] + red[3]);

  ushort4 p0; p0.x=f2bf(e0x*inv); p0.y=f2bf(e0y*inv); p0.z=f2bf(e0z*inv); p0.w=f2bf(e0w*inv);
  ushort4 p1; p1.x=f2bf(e1x*inv); p1.y=f2bf(e1y*inv); p1.z=f2bf(e1z*inv); p1.w=f2bf(e1w*inv);
  ((ushort4*)dst)[t]       = p0;
  ((ushort4*)dst)[t + 256] = p1;
}

// ---------------------------------------------------------------------------
extern "C" void kernel_launch(void* const* d_in, const int* in_sizes, int n_in,
                              void* d_out, int out_size, void* d_ws, size_t ws_size,
                              hipStream_t stream) {
  const float* lidar  = (const float*)d_in[0];   // [B,N,D]
  const float* camera = (const float*)d_in[1];   // [B,M,D]
  const float* lconf  = (const float*)d_in[2];   // [B,N,1]
  // d_in[3] camera_confidence: unused by the reference
  const float* Wq = (const float*)d_in[4];
  const float* bq = (const float*)d_in[5];
  const float* Wk = (const float*)d_in[6];
  // d_in[7] bk: row-constant in scores -> softmax-invariant, dropped
  const float* Wv = (const float*)d_in[8];
  const float* bv = (const float*)d_in[9];
  float* out = (float*)d_out;                    // [B,N,D] f32

  // workspace layout (bytes), total ~208 MB
  char* ws = (char*)d_ws;
  float*          scores = (float*)(ws + 0);                  // [B,N,M] f32 134.2MB (P bf16 in-place)
  // transient aliases inside the scores region (dead before scores is written):
  unsigned short* liHi   = (unsigned short*)(ws + 0);         // [B,N,D] 16.8MB
  unsigned short* liLo   = (unsigned short*)(ws + 16777216);  // [B,N,D] 16.8MB
  unsigned short* atHi   = (unsigned short*)(ws + 33554432);  // [D,D]   0.5MB
  unsigned short* atLo   = (unsigned short*)(ws + 34078720);  // [D,D]   0.5MB
  float*          c2     = (float*)(ws + 34603008);           // [D]
  unsigned short* wvH    = (unsigned short*)(ws + 34605056);  // [D,D]   0.5MB
  // persistent:
  unsigned short* Thi    = (unsigned short*)(ws + 134217728); // [B,N,D] 16.8MB
  unsigned short* Tlo    = (unsigned short*)(ws + 150994944); // [B,N,D] 16.8MB
  unsigned short* camHi  = (unsigned short*)(ws + 167772160); // [B,M,D] 16.8MB
  unsigned short* camLo  = (unsigned short*)(ws + 184549376); // [B,M,D] 16.8MB
  unsigned short* Vt     = (unsigned short*)(ws + 201326592); // [B,D,M] 16.8MB
  float*          svec   = (float*)(ws + 218103808);          // [B,M]

  // pre-splits
  split2_kernel<<<dim3(2048), 256, 0, stream>>>(camera, camHi, camLo, BB*MM*DD/4);
  split2_kernel<<<dim3(2048), 256, 0, stream>>>(lidar,  liHi,  liLo,  BB*NN*DD/4);
  split2_kernel<<<dim3(512),  256, 0, stream>>>(Wv,     wvH,   nullptr, DD*DD/4);
  at_kernel<<<dim3(16,16), 256, 0, stream>>>(Wq, Wk, atHi, atLo);
  c2_kernel<<<dim3(2), 256, 0, stream>>>(bq, Wk, c2);
  s_kernel<<<dim3(BB*MM), 64, 0, stream>>>(camera, c2, svec);

  // T = lidar @ At^T (x3) -> Thi/Tlo.   out cols 512 -> grid.x = 2
  gemm_x3<4><<<dim3(DD/256, NN/128, BB), 256, 0, stream>>>(
      liHi, liLo, (long)NN*DD, DD,
      atHi, atLo, 0, DD,
      Thi, Tlo, (long)NN*DD, DD, DD, nullptr, nullptr);

  // Vt[e,m] = Wv[e,:].cam[m,:] + bv[e]  (plain bf16)
  gemm_bf<1><<<dim3(MM/128, DD/128, BB), 256, 0, stream>>>(
      wvH, 0, DD,
      camHi, (long)MM*DD, DD,
      Vt, (long)DD*MM, MM, DD, bv);

  // scores = conf * (T @ cam^T + svec)  (x3)
  gemm_x3<2><<<dim3(MM/256, NN/128, BB), 256, 0, stream>>>(
      Thi, Tlo, (long)NN*DD, DD,
      camHi, camLo, (long)MM*DD, DD,
      scores, nullptr, (long)NN*MM, MM, DD, lconf, svec);

  // row softmax, P bf16 in-place
  softmax_kernel<<<dim3(BB*NN), 256, 0, stream>>>(scores);

  // out = P @ Vt^T  (plain bf16)
  gemm_bf<0><<<dim3(DD/128, NN/128, BB), 256, 0, stream>>>(
      (const unsigned short*)scores, (long)NN*2*MM, 2*MM,
      Vt, (long)DD*MM, MM,
      out, (long)NN*DD, DD, MM, nullptr);
}

// Round 3
// 321.084 us; speedup vs baseline: 1.3063x; 1.3063x over previous
//
#include <hip/hip_runtime.h>
#include <hip/hip_bf16.h>

#define BB 8
#define NN 2048
#define MM 2048
#define DD 512

typedef __attribute__((ext_vector_type(8))) short bf16x8;
typedef __attribute__((ext_vector_type(4))) float f32x4;
typedef __attribute__((ext_vector_type(8))) unsigned short u16x8;

__device__ __forceinline__ unsigned short f2bf(float x){
  unsigned int u = __float_as_uint(x);
  u += 0x7fffu + ((u>>16)&1u);   // round-to-nearest-even
  return (unsigned short)(u>>16);
}
__device__ __forceinline__ float bf2f(unsigned short h){
  return __uint_as_float(((unsigned int)h)<<16);
}
__device__ __forceinline__ f32x4 mfma16(bf16x8 a, bf16x8 b, f32x4 c){
  return __builtin_amdgcn_mfma_f32_16x16x32_bf16(a, b, c, 0, 0, 0);
}

// batch->XCD swizzle: flat id f -> bz = f&7 (XCD presumed f%8), bijective
// (requires gridDim.z == 8)
__device__ __forceinline__ void swz_xyz(int& bn, int& bm, int& bz){
  int f = ((int)blockIdx.z * (int)gridDim.y + (int)blockIdx.y) * (int)gridDim.x
        + (int)blockIdx.x;
  bz = f & 7;
  int r = f >> 3;
  bn = r % (int)gridDim.x;
  bm = r / (int)gridDim.x;
}

// ---------------------------------------------------------------------------
// split2: f32 -> hi/lo bf16 (lo==nullptr -> hi only), float4-vectorized
// ---------------------------------------------------------------------------
__global__ __launch_bounds__(256) void split2_kernel(const float* __restrict__ in,
    unsigned short* __restrict__ hi, unsigned short* __restrict__ lo, int n4){
  int i = blockIdx.x*256 + threadIdx.x;
  const int stride = gridDim.x*256;
  for (; i < n4; i += stride){
    float4 v = ((const float4*)in)[i];
    ushort4 h; h.x=f2bf(v.x); h.y=f2bf(v.y); h.z=f2bf(v.z); h.w=f2bf(v.w);
    ((ushort4*)hi)[i] = h;
    if (lo){
      ushort4 l;
      l.x=f2bf(v.x-bf2f(h.x)); l.y=f2bf(v.y-bf2f(h.y));
      l.z=f2bf(v.z-bf2f(h.z)); l.w=f2bf(v.w-bf2f(h.w));
      ((ushort4*)lo)[i] = l;
    }
  }
}

// ---------------------------------------------------------------------------
// K0: At[j][i] = sum_e Wq[e][i] * Wk[e][j], written split hi/lo bf16
// ---------------------------------------------------------------------------
__global__ __launch_bounds__(256) void at_kernel(const float* __restrict__ Wq,
                                                 const float* __restrict__ Wk,
                                                 unsigned short* __restrict__ atHi,
                                                 unsigned short* __restrict__ atLo){
  const int i0 = blockIdx.x * 32, j0 = blockIdx.y * 32;
  __shared__ float q_s[32][33];
  __shared__ float k_s[32][33];
  const int t = threadIdx.x;
  const int tx = t & 15, ty = t >> 4;
  float acc[2][2] = {{0.f,0.f},{0.f,0.f}};
  for (int e0 = 0; e0 < DD; e0 += 32){
    __syncthreads();
#pragma unroll
    for (int p = 0; p < 4; ++p){
      int idx = t + 256*p;
      int e = idx >> 5, c = idx & 31;
      q_s[e][c] = Wq[(size_t)(e0+e)*DD + i0 + c];
      k_s[e][c] = Wk[(size_t)(e0+e)*DD + j0 + c];
    }
    __syncthreads();
#pragma unroll 8
    for (int e = 0; e < 32; ++e){
      float q0 = q_s[e][2*tx], q1 = q_s[e][2*tx+1];
      float k0 = k_s[e][2*ty], k1 = k_s[e][2*ty+1];
      acc[0][0] += k0*q0; acc[0][1] += k0*q1;
      acc[1][0] += k1*q0; acc[1][1] += k1*q1;
    }
  }
#pragma unroll
  for (int a = 0; a < 2; ++a)
#pragma unroll
    for (int b = 0; b < 2; ++b){
      float v = acc[a][b];
      size_t idx = (size_t)(j0 + 2*ty + a)*DD + i0 + 2*tx + b;
      unsigned short h = f2bf(v);
      atHi[idx] = h;
      atLo[idx] = f2bf(v - bf2f(h));
    }
}

// c2[d] = sum_e bq[e] * Wk[e][d]
__global__ __launch_bounds__(256) void c2_kernel(const float* __restrict__ bq,
                                                 const float* __restrict__ Wk,
                                                 float* __restrict__ c2){
  int d = blockIdx.x * 256 + threadIdx.x;
  float a = 0.f;
  for (int e = 0; e < DD; ++e) a += bq[e] * Wk[(size_t)e*DD + d];
  c2[d] = a;
}

// s[b*M+m] = dot(camera[b,m,:], c2)
__global__ __launch_bounds__(64) void s_kernel(const float* __restrict__ cam,
                                               const float* __restrict__ c2,
                                               float* __restrict__ svec){
  size_t row = blockIdx.x;
  const float* y = cam + row * DD;
  int l = threadIdx.x;
  float a = 0.f;
#pragma unroll
  for (int i = 0; i < 8; ++i) a += y[l + 64*i] * c2[l + 64*i];
  for (int o = 32; o; o >>= 1) a += __shfl_xor(a, o);
  if (l == 0) svec[row] = a;
}

// ---------------------------------------------------------------------------
// scores x3 GEMM: O[row,col] = conf[row]*(sum_k A[row,k]*B[col,k] + svec[col])
// A = Thi+Tlo, B = camHi+camLo.  Block 128(rows) x 256(cols), 4 waves,
// wave tile 128x64 (8x4 fragments).  acc = hh + hl + lh.
// ---------------------------------------------------------------------------
__global__ __launch_bounds__(256, 2) void gemm_scores(
    const unsigned short* __restrict__ Ahg, const unsigned short* __restrict__ Alg,
    const unsigned short* __restrict__ Bhg, const unsigned short* __restrict__ Blg,
    float* __restrict__ O,
    const float* __restrict__ conf, const float* __restrict__ svec)
{
  __shared__ __attribute__((aligned(16))) unsigned short Ah[128][40];
  __shared__ __attribute__((aligned(16))) unsigned short Al[128][40];
  __shared__ __attribute__((aligned(16))) unsigned short Bh[256][40];
  __shared__ __attribute__((aligned(16))) unsigned short Bl[256][40];

  int bn, bm, bz; swz_xyz(bn, bm, bz);
  const int t = threadIdx.x;
  const int lane = t & 63, w = t >> 6;
  const int lr = lane & 15, lk = (lane >> 4) << 3;

  f32x4 acc[8][4];
#pragma unroll
  for (int m = 0; m < 8; ++m)
#pragma unroll
    for (int n = 0; n < 4; ++n){ f32x4 z = {0.f,0.f,0.f,0.f}; acc[m][n] = z; }

  const size_t offA = (size_t)bz*((size_t)NN*DD) + ((size_t)bm*128)*DD;
  const size_t offB = (size_t)bz*((size_t)MM*DD) + ((size_t)bn*256)*DD;
  const unsigned short* Ahp = Ahg + offA;
  const unsigned short* Alp = Alg + offA;
  const unsigned short* Bhp = Bhg + offB;
  const unsigned short* Blp = Blg + offB;

  const int sr = t >> 2;          // 0..63
  const int sc = (t & 3) * 8;     // 0,8,16,24

  for (int k0 = 0; k0 < DD; k0 += 32){
    __syncthreads();
#pragma unroll
    for (int p = 0; p < 2; ++p){
      int r = sr + 64*p;
      *(u16x8*)&Ah[r][sc] = *(const u16x8*)(Ahp + (size_t)r*DD + k0 + sc);
      *(u16x8*)&Al[r][sc] = *(const u16x8*)(Alp + (size_t)r*DD + k0 + sc);
    }
#pragma unroll
    for (int p = 0; p < 4; ++p){
      int r = sr + 64*p;
      *(u16x8*)&Bh[r][sc] = *(const u16x8*)(Bhp + (size_t)r*DD + k0 + sc);
      *(u16x8*)&Bl[r][sc] = *(const u16x8*)(Blp + (size_t)r*DD + k0 + sc);
    }
    __syncthreads();

    bf16x8 bhf[4], blf[4];
#pragma unroll
    for (int n = 0; n < 4; ++n){
      bhf[n] = *(const bf16x8*)&Bh[w*64 + n*16 + lr][lk];
      blf[n] = *(const bf16x8*)&Bl[w*64 + n*16 + lr][lk];
    }
#pragma unroll
    for (int m = 0; m < 8; ++m){
      bf16x8 ahf = *(const bf16x8*)&Ah[m*16 + lr][lk];
      bf16x8 alf = *(const bf16x8*)&Al[m*16 + lr][lk];
#pragma unroll
      for (int n = 0; n < 4; ++n){
        acc[m][n] = mfma16(ahf, bhf[n], acc[m][n]);
        acc[m][n] = mfma16(ahf, blf[n], acc[m][n]);
        acc[m][n] = mfma16(alf, bhf[n], acc[m][n]);
      }
    }
  }

  const int ocol0 = bn*256 + w*64;
  const int orow0 = bm*128;
#pragma unroll
  for (int m = 0; m < 8; ++m){
#pragma unroll
    for (int n = 0; n < 4; ++n){
      int col  = ocol0 + n*16 + lr;
      int row0 = orow0 + m*16 + ((lane >> 4) << 2);
#pragma unroll
      for (int r = 0; r < 4; ++r){
        int row = row0 + r;
        O[(size_t)bz*((size_t)NN*MM) + (size_t)row*MM + col]
            = conf[bz*NN + row] * (acc[m][n][r] + svec[bz*MM + col]);
      }
    }
  }
}

// ---------------------------------------------------------------------------
// T x3 GEMM: T[row,col] = sum_k lidar[row,k]*At[col,k], hi/lo bf16 out.
// Block 128x128, 4 waves 2x2, wave 64x64 (4x4 frags).
// ---------------------------------------------------------------------------
__global__ __launch_bounds__(256) void gemm_T(
    const unsigned short* __restrict__ Ahg, const unsigned short* __restrict__ Alg,
    const unsigned short* __restrict__ Bhg, const unsigned short* __restrict__ Blg,
    unsigned short* __restrict__ O1, unsigned short* __restrict__ O2)
{
  __shared__ __attribute__((aligned(16))) unsigned short Ah[128][40];
  __shared__ __attribute__((aligned(16))) unsigned short Al[128][40];
  __shared__ __attribute__((aligned(16))) unsigned short Bh[128][40];
  __shared__ __attribute__((aligned(16))) unsigned short Bl[128][40];

  int bn, bm, bz; swz_xyz(bn, bm, bz);
  const int t = threadIdx.x;
  const int lane = t & 63, w = t >> 6;
  const int wrow = w >> 1, wcol = w & 1;
  const int lr = lane & 15, lk = (lane >> 4) << 3;

  f32x4 acc[4][4];
#pragma unroll
  for (int m = 0; m < 4; ++m)
#pragma unroll
    for (int n = 0; n < 4; ++n){ f32x4 z = {0.f,0.f,0.f,0.f}; acc[m][n] = z; }

  const size_t offA = (size_t)bz*((size_t)NN*DD) + ((size_t)bm*128)*DD;
  const size_t offB = ((size_t)bn*128)*DD;   // At shared across batches
  const unsigned short* Ahp = Ahg + offA;
  const unsigned short* Alp = Alg + offA;
  const unsigned short* Bhp = Bhg + offB;
  const unsigned short* Blp = Blg + offB;

  const int sr = t >> 2;
  const int sc = (t & 3) * 8;

  for (int k0 = 0; k0 < DD; k0 += 32){
    __syncthreads();
#pragma unroll
    for (int p = 0; p < 2; ++p){
      int r = sr + 64*p;
      *(u16x8*)&Ah[r][sc] = *(const u16x8*)(Ahp + (size_t)r*DD + k0 + sc);
      *(u16x8*)&Al[r][sc] = *(const u16x8*)(Alp + (size_t)r*DD + k0 + sc);
      *(u16x8*)&Bh[r][sc] = *(const u16x8*)(Bhp + (size_t)r*DD + k0 + sc);
      *(u16x8*)&Bl[r][sc] = *(const u16x8*)(Blp + (size_t)r*DD + k0 + sc);
    }
    __syncthreads();

    bf16x8 ah[4], al[4], bh[4], bl[4];
#pragma unroll
    for (int m = 0; m < 4; ++m){
      ah[m] = *(const bf16x8*)&Ah[wrow*64 + m*16 + lr][lk];
      al[m] = *(const bf16x8*)&Al[wrow*64 + m*16 + lr][lk];
    }
#pragma unroll
    for (int n = 0; n < 4; ++n){
      bh[n] = *(const bf16x8*)&Bh[wcol*64 + n*16 + lr][lk];
      bl[n] = *(const bf16x8*)&Bl[wcol*64 + n*16 + lr][lk];
    }
#pragma unroll
    for (int m = 0; m < 4; ++m)
#pragma unroll
      for (int n = 0; n < 4; ++n){
        acc[m][n] = mfma16(ah[m], bh[n], acc[m][n]);
        acc[m][n] = mfma16(ah[m], bl[n], acc[m][n]);
        acc[m][n] = mfma16(al[m], bh[n], acc[m][n]);
      }
  }

  const int orow = bm*128 + wrow*64;
  const int ocol = bn*128 + wcol*64;
#pragma unroll
  for (int m = 0; m < 4; ++m){
#pragma unroll
    for (int n = 0; n < 4; ++n){
      int col  = ocol + n*16 + lr;
      int row0 = orow + m*16 + ((lane >> 4) << 2);
#pragma unroll
      for (int r = 0; r < 4; ++r){
        int row = row0 + r;
        float v = acc[m][n][r];
        size_t idx = (size_t)bz*((size_t)NN*DD) + (size_t)row*DD + col;
        unsigned short h = f2bf(v);
        O1[idx] = h;
        O2[idx] = f2bf(v - bf2f(h));
      }
    }
  }
}

// ---------------------------------------------------------------------------
// Vt GEMM: Vt[e,m] = sum_k Wv[e,k]*cam[m,k] + bv[e], bf16 out.
// Block 128x128, 4 waves 2x2.
// ---------------------------------------------------------------------------
__global__ __launch_bounds__(256) void gemm_Vt(
    const unsigned short* __restrict__ Ag,   // wvH [D][D]
    const unsigned short* __restrict__ Bg,   // camHi [B,M,D]
    unsigned short* __restrict__ O,          // Vt [B,D,M]
    const float* __restrict__ bias)
{
  __shared__ __attribute__((aligned(16))) unsigned short Ah[128][40];
  __shared__ __attribute__((aligned(16))) unsigned short Bh[128][40];

  int bn, bm, bz; swz_xyz(bn, bm, bz);
  const int t = threadIdx.x;
  const int lane = t & 63, w = t >> 6;
  const int wrow = w >> 1, wcol = w & 1;
  const int lr = lane & 15, lk = (lane >> 4) << 3;

  f32x4 acc[4][4];
#pragma unroll
  for (int m = 0; m < 4; ++m)
#pragma unroll
    for (int n = 0; n < 4; ++n){ f32x4 z = {0.f,0.f,0.f,0.f}; acc[m][n] = z; }

  const unsigned short* Ap = Ag + ((size_t)bm*128)*DD;
  const unsigned short* Bp = Bg + (size_t)bz*((size_t)MM*DD) + ((size_t)bn*128)*DD;

  const int sr = t >> 2;
  const int sc = (t & 3) * 8;

  for (int k0 = 0; k0 < DD; k0 += 32){
    __syncthreads();
#pragma unroll
    for (int p = 0; p < 2; ++p){
      int r = sr + 64*p;
      *(u16x8*)&Ah[r][sc] = *(const u16x8*)(Ap + (size_t)r*DD + k0 + sc);
      *(u16x8*)&Bh[r][sc] = *(const u16x8*)(Bp + (size_t)r*DD + k0 + sc);
    }
    __syncthreads();

    bf16x8 af[4], bf[4];
#pragma unroll
    for (int m = 0; m < 4; ++m) af[m] = *(const bf16x8*)&Ah[wrow*64 + m*16 + lr][lk];
#pragma unroll
    for (int n = 0; n < 4; ++n) bf[n] = *(const bf16x8*)&Bh[wcol*64 + n*16 + lr][lk];
#pragma unroll
    for (int m = 0; m < 4; ++m)
#pragma unroll
      for (int n = 0; n < 4; ++n)
        acc[m][n] = mfma16(af[m], bf[n], acc[m][n]);
  }

  const int orow = bm*128 + wrow*64;   // e (V col)
  const int ocol = bn*128 + wcol*64;   // m (cam row)
#pragma unroll
  for (int m = 0; m < 4; ++m){
#pragma unroll
    for (int n = 0; n < 4; ++n){
      int col  = ocol + n*16 + lr;
      int row0 = orow + m*16 + ((lane >> 4) << 2);
#pragma unroll
      for (int r = 0; r < 4; ++r){
        int row = row0 + r;
        O[(size_t)bz*((size_t)DD*MM) + (size_t)row*MM + col] = f2bf(acc[m][n][r] + bias[row]);
      }
    }
  }
}

// ---------------------------------------------------------------------------
// PV GEMM: out[n,e] = sum_m P[n,m]*Vt[e,m].  Block 64(rows) x 256(cols),
// 4 waves 1x4, wave 64x64.  P bf16 at lda=2*MM (in-place in scores buffer).
// ---------------------------------------------------------------------------
__global__ __launch_bounds__(256) void gemm_pv(
    const unsigned short* __restrict__ P,
    const unsigned short* __restrict__ V,
    float* __restrict__ O)
{
  __shared__ __attribute__((aligned(16))) unsigned short Ah[64][40];
  __shared__ __attribute__((aligned(16))) unsigned short Bh[256][40];

  int bn, bm, bz; swz_xyz(bn, bm, bz);
  const int t = threadIdx.x;
  const int lane = t & 63, w = t >> 6;
  const int lr = lane & 15, lk = (lane >> 4) << 3;

  f32x4 acc[4][4];
#pragma unroll
  for (int m = 0; m < 4; ++m)
#pragma unroll
    for (int n = 0; n < 4; ++n){ f32x4 z = {0.f,0.f,0.f,0.f}; acc[m][n] = z; }

  const unsigned short* Ap = P + (size_t)bz*((size_t)NN*2*MM) + ((size_t)bm*64)*(2*MM);
  const unsigned short* Bp = V + (size_t)bz*((size_t)DD*MM) + ((size_t)bn*256)*MM;

  const int sr = t >> 2;          // 0..63
  const int sc = (t & 3) * 8;

  for (int k0 = 0; k0 < MM; k0 += 32){
    __syncthreads();
    *(u16x8*)&Ah[sr][sc] = *(const u16x8*)(Ap + (size_t)sr*(2*MM) + k0 + sc);
#pragma unroll
    for (int p = 0; p < 4; ++p){
      int r = sr + 64*p;
      *(u16x8*)&Bh[r][sc] = *(const u16x8*)(Bp + (size_t)r*MM + k0 + sc);
    }
    __syncthreads();

    bf16x8 af[4], bf[4];
#pragma unroll
    for (int m = 0; m < 4; ++m) af[m] = *(const bf16x8*)&Ah[m*16 + lr][lk];
#pragma unroll
    for (int n = 0; n < 4; ++n) bf[n] = *(const bf16x8*)&Bh[w*64 + n*16 + lr][lk];
#pragma unroll
    for (int m = 0; m < 4; ++m)
#pragma unroll
      for (int n = 0; n < 4; ++n)
        acc[m][n] = mfma16(af[m], bf[n], acc[m][n]);
  }

  const int orow0 = bm*64;
  const int ocol0 = bn*256 + w*64;
#pragma unroll
  for (int m = 0; m < 4; ++m){
#pragma unroll
    for (int n = 0; n < 4; ++n){
      int col  = ocol0 + n*16 + lr;
      int row0 = orow0 + m*16 + ((lane >> 4) << 2);
#pragma unroll
      for (int r = 0; r < 4; ++r){
        int row = row0 + r;
        O[(size_t)bz*((size_t)NN*DD) + (size_t)row*DD + col] = acc[m][n][r];
      }
    }
  }
}

// ---------------------------------------------------------------------------
// Row softmax over M=2048, f32 in, bf16 out in-place (row's first 4KB)
// ---------------------------------------------------------------------------
__global__ __launch_bounds__(256) void softmax_kernel(float* __restrict__ scores){
  const size_t row = blockIdx.x;
  float* src = scores + row * MM;
  unsigned short* dst = (unsigned short*)scores + row * (size_t)(2*MM);
  const int t = threadIdx.x;

  float4 v0 = ((const float4*)src)[t];
  float4 v1 = ((const float4*)src)[t + 256];

  float mx = fmaxf(fmaxf(fmaxf(v0.x,v0.y), fmaxf(v0.z,v0.w)),
                   fmaxf(fmaxf(v1.x,v1.y), fmaxf(v1.z,v1.w)));
  for (int o = 32; o; o >>= 1) mx = fmaxf(mx, __shfl_xor(mx, o));
  __shared__ float red[4];
  if ((t & 63) == 0) red[t >> 6] = mx;
  __syncthreads();
  mx = fmaxf(fmaxf(red[0], red[1]), fmaxf(red[2], red[3]));

  float e0x = __expf(v0.x - mx), e0y = __expf(v0.y - mx);
  float e0z = __expf(v0.z - mx), e0w = __expf(v0.w - mx);
  float e1x = __expf(v1.x - mx), e1y = __expf(v1.y - mx);
  float e1z = __expf(v1.z - mx), e1w = __expf(v1.w - mx);
  float s = e0x+e0y+e0z+e0w+e1x+e1y+e1z+e1w;
  for (int o = 32; o; o >>= 1) s += __shfl_xor(s, o);
  __syncthreads();
  if ((t & 63) == 0) red[t >> 6] = s;
  __syncthreads();
  float inv = 1.f / (red[0] + red[1] + red[2] + red[3]);

  ushort4 p0; p0.x=f2bf(e0x*inv); p0.y=f2bf(e0y*inv); p0.z=f2bf(e0z*inv); p0.w=f2bf(e0w*inv);
  ushort4 p1; p1.x=f2bf(e1x*inv); p1.y=f2bf(e1y*inv); p1.z=f2bf(e1z*inv); p1.w=f2bf(e1w*inv);
  ((ushort4*)dst)[t]       = p0;
  ((ushort4*)dst)[t + 256] = p1;
}

// ---------------------------------------------------------------------------
extern "C" void kernel_launch(void* const* d_in, const int* in_sizes, int n_in,
                              void* d_out, int out_size, void* d_ws, size_t ws_size,
                              hipStream_t stream) {
  const float* lidar  = (const float*)d_in[0];   // [B,N,D]
  const float* camera = (const float*)d_in[1];   // [B,M,D]
  const float* lconf  = (const float*)d_in[2];   // [B,N,1]
  // d_in[3] camera_confidence: unused by the reference
  const float* Wq = (const float*)d_in[4];
  const float* bq = (const float*)d_in[5];
  const float* Wk = (const float*)d_in[6];
  // d_in[7] bk: row-constant in scores -> softmax-invariant, dropped
  const float* Wv = (const float*)d_in[8];
  const float* bv = (const float*)d_in[9];
  float* out = (float*)d_out;                    // [B,N,D] f32

  // workspace layout (bytes), total ~218 MB
  char* ws = (char*)d_ws;
  float*          scores = (float*)(ws + 0);                  // [B,N,M] f32 134.2MB (P bf16 in-place)
  // transient aliases inside scores region (dead before scores is written):
  unsigned short* liHi   = (unsigned short*)(ws + 0);         // [B,N,D] 16.8MB
  unsigned short* liLo   = (unsigned short*)(ws + 16777216);  // [B,N,D] 16.8MB
  unsigned short* atHi   = (unsigned short*)(ws + 33554432);  // [D,D]   0.5MB
  unsigned short* atLo   = (unsigned short*)(ws + 34078720);  // [D,D]   0.5MB
  float*          c2     = (float*)(ws + 34603008);           // [D]
  unsigned short* wvH    = (unsigned short*)(ws + 34605056);  // [D,D]   0.5MB
  // persistent:
  unsigned short* Thi    = (unsigned short*)(ws + 134217728); // [B,N,D] 16.8MB
  unsigned short* Tlo    = (unsigned short*)(ws + 150994944); // [B,N,D] 16.8MB
  unsigned short* camHi  = (unsigned short*)(ws + 167772160); // [B,M,D] 16.8MB
  unsigned short* camLo  = (unsigned short*)(ws + 184549376); // [B,M,D] 16.8MB
  unsigned short* Vt     = (unsigned short*)(ws + 201326592); // [B,D,M] 16.8MB
  float*          svec   = (float*)(ws + 218103808);          // [B,M]

  // pre-splits
  split2_kernel<<<dim3(2048), 256, 0, stream>>>(camera, camHi, camLo, BB*MM*DD/4);
  split2_kernel<<<dim3(2048), 256, 0, stream>>>(lidar,  liHi,  liLo,  BB*NN*DD/4);
  split2_kernel<<<dim3(512),  256, 0, stream>>>(Wv,     wvH,   nullptr, DD*DD/4);
  at_kernel<<<dim3(16,16), 256, 0, stream>>>(Wq, Wk, atHi, atLo);
  c2_kernel<<<dim3(2), 256, 0, stream>>>(bq, Wk, c2);
  s_kernel<<<dim3(BB*MM), 64, 0, stream>>>(camera, c2, svec);

  // T = lidar @ At^T (x3) -> Thi/Tlo
  gemm_T<<<dim3(DD/128, NN/128, BB), 256, 0, stream>>>(
      liHi, liLo, atHi, atLo, Thi, Tlo);

  // Vt[e,m] = Wv[e,:].cam[m,:] + bv[e]
  gemm_Vt<<<dim3(MM/128, DD/128, BB), 256, 0, stream>>>(
      wvH, camHi, Vt, bv);

  // scores = conf * (T @ cam^T + svec)  (x3)
  gemm_scores<<<dim3(MM/256, NN/128, BB), 256, 0, stream>>>(
      Thi, Tlo, camHi, camLo, scores, lconf, svec);

  // row softmax, P bf16 in-place
  softmax_kernel<<<dim3(BB*NN), 256, 0, stream>>>(scores);

  // out = P @ Vt^T
  gemm_pv<<<dim3(DD/256, NN/64, BB), 256, 0, stream>>>(
      (const unsigned short*)scores, Vt, out);
}